// Round 12
// baseline (1048.455 us; speedup 1.0000x reference)
//
#include <hip/hip_runtime.h>
#include <hip/hip_bf16.h>
#include <math.h>

#define NN 50000
#define NE 800000
#define ET (NE + NN)
#define DCAP 48        // CSR slots/node (Poisson(17): P(deg>=48)~2e-9 -> ovf fallback)
#define MAXOVF 8192
#define NBIN 196       // binning blocks; block b owns nodes [b*256, b*256+256)
#define NG1 1563       // gemm blocks: ceil(NN/32)
#define NFB (NBIN + NG1)
#define NCB 832        // compact grid
#define NNP (NBIN * 256)   // padded node count for csrF (50176)

__device__ __forceinline__ float bf2f(unsigned short u) {
    return __uint_as_float(((unsigned)u) << 16);
}
__device__ __forceinline__ unsigned short f2bf(float f) {   // RNE
    unsigned u = __float_as_uint(f);
    return (unsigned short)((u + 0x7fff + ((u >> 16) & 1)) >> 16);
}
__device__ __forceinline__ float lrelu(float e) {
    return e >= 0.f ? e : 0.2f * e;
}

// ---------- compact: edges -> packed uint32 (dst<<16|src) + wsm convert ----------
// pk is the 3.4MB stream the 196 binning blocks re-scan (L2/L3-resident).
__global__ __launch_bounds__(256) void k_compact(const void* __restrict__ xraw,
                                                 const void* __restrict__ ei,
                                                 const void* p2, const void* p3, const void* p4, const void* p5,
                                                 const void* p6, const void* p7, const void* p8, const void* p9,
                                                 unsigned int* __restrict__ pk,
                                                 float* __restrict__ wsm) {
    __shared__ int wred[8];
    int t = threadIdx.x;
    const unsigned long long* e64u = (const unsigned long long*)ei;
    const unsigned int* x32 = (const unsigned int*)xraw;
    int ci = 0, cf = 0;
    #pragma unroll
    for (int q = 0; q < 4; q++) {
        if (e64u[4 * t + q] >= (unsigned long long)NN) ci = 1;
        unsigned ex = (x32[4 * t + q] >> 7) & 0xFFu;
        cf += (ex >= 96 && ex <= 140) ? 1 : 0;
    }
    #pragma unroll
    for (int off = 32; off; off >>= 1) { ci |= __shfl_xor(ci, off); cf += __shfl_xor(cf, off); }
    if ((t & 63) == 0) { wred[t >> 6] = ci; wred[4 + (t >> 6)] = cf; }
    __syncthreads();
    int iflag = (wred[0] | wred[1] | wred[2] | wred[3]) ? 0 : 1;  // 1 = int64
    int fl = ((wred[4] + wred[5] + wred[6] + wred[7]) > 700) ? 1 : 0;  // 1 = bf16

    int g0 = blockIdx.x * 256 + t;
    if (g0 < 10528) {
        const void* p; int off;
        if (g0 < 8192)       { p = p2; off = g0; }
        else if (g0 < 8256)  { p = p3; off = g0 - 8192; }
        else if (g0 < 8320)  { p = p4; off = g0 - 8256; }
        else if (g0 < 8384)  { p = p5; off = g0 - 8320; }
        else if (g0 < 10432) { p = p6; off = g0 - 8384; }
        else if (g0 < 10464) { p = p7; off = g0 - 10432; }
        else if (g0 < 10496) { p = p8; off = g0 - 10464; }
        else                 { p = p9; off = g0 - 10496; }
        wsm[g0] = fl ? bf2f(((const unsigned short*)p)[off]) : ((const float*)p)[off];
    }
    const long long* e64s = (const long long*)ei;
    const int* e32s = (const int*)ei;
    for (int e = g0; e < NE; e += NCB * 256) {
        unsigned s, d;
        if (iflag) { s = (unsigned)e64s[e]; d = (unsigned)e64s[NE + e]; }
        else       { s = (unsigned)e32s[e]; d = (unsigned)e32s[NE + e]; }
        pk[e] = (d << 16) | s;
    }
    for (int i = g0; i < NN; i += NCB * 256) {   // self-loops
        pk[NE + i] = ((unsigned)i << 16) | (unsigned)i;
    }
}

// ---------- fused front: SINGLE-WRITER binned CSR (blocks 0..195) | GEMM1+al1 ----------
// R11 analysis: scattered slot writes cost 38-56MB because each csrF line is
// written from all 8 XCDs (75K lines x 8 x 64B = 38MB floor). Fix: block b bins
// its 256 owned nodes' edges in LDS (scan pk 196x, L2-resident), then writes
// csrF CONTIGUOUSLY -> one writer per line, writes drop to the 4.8MB payload.
// Bin blocks head the grid so they co-reside with gemm (complementary pipes).
__global__ __launch_bounds__(256) void k_front(const void* __restrict__ xraw,
                                               const void* __restrict__ w1raw,
                                               const void* __restrict__ as1raw,
                                               const void* __restrict__ ad1raw,
                                               const unsigned int* __restrict__ pk,
                                               unsigned short* __restrict__ h1b,
                                               float* __restrict__ als, float* __restrict__ ald,
                                               unsigned short* __restrict__ csrF, int* __restrict__ deg,
                                               int2* __restrict__ ovf, int* __restrict__ ovfcnt) {
    __shared__ unsigned int shbuf[8384];   // union: gemm {Wp 4160 | xt 4224} / bin {cnt 256 | rows 6144}
    __shared__ int wred[4];
    int tid = threadIdx.x;
    int b = blockIdx.x;

    if (b < NBIN) {
        // ===== binned CSR build: single writer for nodes [base, base+256) =====
        int base = b * 256;
        int* cnt = (int*)shbuf;
        unsigned short* rows = (unsigned short*)(shbuf + 256);
        cnt[tid] = 0;
        __syncthreads();
        for (int e = tid; e < ET; e += 256) {
            unsigned v = pk[e];
            unsigned r = (v >> 16) - (unsigned)base;
            if (r < 256u) {
                int slot = atomicAdd(&cnt[r], 1);
                if (slot < DCAP) rows[r * DCAP + slot] = (unsigned short)(v & 0xFFFFu);
                else {
                    int o = atomicAdd(ovfcnt, 1);
                    if (o < MAXOVF) ovf[o] = make_int2((int)(v & 0xFFFFu), (int)(v >> 16));
                }
            }
        }
        __syncthreads();
        int n = base + tid;
        if (n < NN) deg[n] = cnt[tid];
        // contiguous coalesced row write: 256*DCAP*2 B = 1536 uint4
        uint4* dstp = (uint4*)(csrF + (size_t)base * DCAP);
        const uint4* srcp = (const uint4*)rows;
        #pragma unroll
        for (int i = 0; i < (256 * DCAP * 2) / (16 * 256); i++)
            dstp[i * 256 + tid] = srcp[i * 256 + tid];
        return;
    }

    // ===== gemm phase (blocks NBIN..NFB-1) =====
    int rb = (b - NBIN) * 32;
    unsigned int* Wp = shbuf;                  // [64*65]
    float* xt = (float*)(shbuf + 4160);        // [32*132]

    // per-block float-dtype detection (x[0..1023], L2-broadcast)
    const unsigned int* x32 = (const unsigned int*)xraw;
    int cf = 0;
    #pragma unroll
    for (int q = 0; q < 4; q++) {
        unsigned ex = (x32[4 * tid + q] >> 7) & 0xFFu;
        cf += (ex >= 96 && ex <= 140) ? 1 : 0;
    }
    #pragma unroll
    for (int off = 32; off; off >>= 1) cf += __shfl_xor(cf, off);
    if ((tid & 63) == 0) wred[tid >> 6] = cf;
    __syncthreads();
    int fl = ((wred[0] + wred[1] + wred[2] + wred[3]) > 700) ? 1 : 0;  // 1 = bf16

    for (int i = tid; i < 64 * 64; i += 256) {
        int k2 = i >> 6, c = i & 63;     // k2 = k/2
        unsigned lo, hi;
        if (fl) {
            lo = ((const unsigned short*)w1raw)[(2 * k2) * 64 + c];
            hi = ((const unsigned short*)w1raw)[(2 * k2 + 1) * 64 + c];
        } else {
            lo = f2bf(((const float*)w1raw)[(2 * k2) * 64 + c]);
            hi = f2bf(((const float*)w1raw)[(2 * k2 + 1) * 64 + c]);
        }
        Wp[c * 65 + k2] = lo | (hi << 16);
    }
    if (fl) {   // bf16 input
        const unsigned short* xb = (const unsigned short*)xraw;
        for (int i = tid; i < 32 * 16; i += 256) {
            int r = i >> 4, k8 = i & 15;
            float f[8];
            if (rb + r < NN) {
                uint4 v = ((const uint4*)xb)[(size_t)(rb + r) * 16 + k8];
                f[0] = bf2f((unsigned short)(v.x & 0xffff)); f[1] = bf2f((unsigned short)(v.x >> 16));
                f[2] = bf2f((unsigned short)(v.y & 0xffff)); f[3] = bf2f((unsigned short)(v.y >> 16));
                f[4] = bf2f((unsigned short)(v.z & 0xffff)); f[5] = bf2f((unsigned short)(v.z >> 16));
                f[6] = bf2f((unsigned short)(v.w & 0xffff)); f[7] = bf2f((unsigned short)(v.w >> 16));
            } else {
                #pragma unroll
                for (int q = 0; q < 8; q++) f[q] = 0.f;
            }
            int o = r * 132 + k8 * 8;
            *(float4*)&xt[o]     = make_float4(f[0], f[1], f[2], f[3]);
            *(float4*)&xt[o + 4] = make_float4(f[4], f[5], f[6], f[7]);
        }
    } else {    // fp32 input
        const float* xf = (const float*)xraw;
        for (int i = tid; i < 32 * 32; i += 256) {
            int r = i >> 5, kq = i & 31;
            float4 v = make_float4(0.f, 0.f, 0.f, 0.f);
            if (rb + r < NN) v = ((const float4*)xf)[(size_t)(rb + r) * 32 + kq];
            *(float4*)&xt[r * 132 + kq * 4] = v;
        }
    }
    __syncthreads();
    int c = tid & 63;
    int rg = tid >> 6;
    float acc[8];
    #pragma unroll
    for (int j = 0; j < 8; j++) acc[j] = 0.f;
    for (int k2 = 0; k2 < 64; k2 += 2) {     // 4 k-values per iteration
        unsigned q0 = Wp[c * 65 + k2];
        unsigned q1 = Wp[c * 65 + k2 + 1];
        float w0 = __uint_as_float(q0 << 16);
        float w1 = __uint_as_float(q0 & 0xffff0000u);
        float w2 = __uint_as_float(q1 << 16);
        float w3 = __uint_as_float(q1 & 0xffff0000u);
        int kk = k2 * 2;
        #pragma unroll
        for (int j = 0; j < 8; j++) {
            float4 xv = *(const float4*)&xt[(rg * 8 + j) * 132 + kk];
            acc[j] = fmaf(xv.x, w0, fmaf(xv.y, w1, fmaf(xv.z, w2, fmaf(xv.w, w3, acc[j]))));
        }
    }
    float asf = fl ? bf2f(((const unsigned short*)as1raw)[c]) : ((const float*)as1raw)[c];
    float adf = fl ? bf2f(((const unsigned short*)ad1raw)[c]) : ((const float*)ad1raw)[c];
    #pragma unroll
    for (int j = 0; j < 8; j++) {
        int r = rb + rg * 8 + j;
        bool ok = r < NN;
        if (ok) h1b[(size_t)r * 64 + c] = f2bf(acc[j]);
        float v = acc[j] * asf, w = acc[j] * adf;
        #pragma unroll
        for (int off = 1; off < 16; off <<= 1) {
            v += __shfl_xor(v, off);
            w += __shfl_xor(w, off);
        }
        if (ok && (c & 15) == 0) {
            als[r * 4 + (c >> 4)] = v;
            ald[r * 4 + (c >> 4)] = w;
        }
    }
}

// ---------- layer-1 aggregation: wave/node; no-max softmax; sum folded into phase C ----------
// |logit| <= ~6 by range analysis -> exp() safe in fp32 without max-shift
__global__ __launch_bounds__(256) void k_agg1(const int* __restrict__ degv, const unsigned short* __restrict__ csrF,
                                              const int2* __restrict__ ovf, const int* __restrict__ ovfcnt,
                                              const float* __restrict__ als, const float* __restrict__ aldv,
                                              const unsigned short* __restrict__ h1b,
                                              const float* __restrict__ b1,
                                              float* __restrict__ out1) {
    __shared__ float pv[4][DCAP * 4];
    __shared__ int  sidx[4][DCAP];
    int w = threadIdx.x >> 6, lane = threadIdx.x & 63;
    int n = blockIdx.x * 4 + w;
    if (n >= NN) return;
    int dg = degv[n];
    const unsigned short* cf = csrF + (size_t)n * DCAP;
    float4 ald = *(const float4*)(aldv + 4 * n);

    if (dg <= DCAP) {
        int sA = 0;
        bool v0 = lane < dg;
        // phase A: compute exp(lrelu(logit)) per edge, store to LDS (no reduction)
        if (v0) {
            sA = cf[lane];
            sidx[w][lane] = sA;
            float4 a = *(const float4*)(als + 4 * sA);
            float4 p;
            p.x = __expf(lrelu(a.x + ald.x)); p.y = __expf(lrelu(a.y + ald.y));
            p.z = __expf(lrelu(a.z + ald.z)); p.w = __expf(lrelu(a.w + ald.w));
            *(float4*)&pv[w][lane * 4] = p;
        }
        // pad to multiple of 4 with zero-weight entries pointing at a valid row
        int degp = (dg + 3) & ~3;
        int s0v = __shfl(sA, 0);
        if (lane >= dg && lane < degp) {
            sidx[w][lane] = s0v;
            *(float4*)&pv[w][lane * 4] = make_float4(0.f, 0.f, 0.f, 0.f);
        }
        // phase C: 4 lane-groups x 16 lanes; lane owns channels j*4..j*4+3 (bf16 uint2)
        // softmax denominator folded in: ps accumulates this lane's head-p per edge
        int g = lane >> 4, j = lane & 15, hh = j >> 2;
        float4 a4 = make_float4(0.f, 0.f, 0.f, 0.f);
        float ps = 0.f;
        for (int e = 0; e < degp; e += 4) {
            int s = sidx[w][e + g];
            float ph = pv[w][(e + g) * 4 + hh];
            uint2 rv = *(const uint2*)&h1b[(size_t)s * 64 + j * 4];
            ps += ph;
            a4.x = fmaf(ph, bf2f((unsigned short)(rv.x & 0xffff)), a4.x);
            a4.y = fmaf(ph, bf2f((unsigned short)(rv.x >> 16)),    a4.y);
            a4.z = fmaf(ph, bf2f((unsigned short)(rv.y & 0xffff)), a4.z);
            a4.w = fmaf(ph, bf2f((unsigned short)(rv.y >> 16)),    a4.w);
        }
        #pragma unroll
        for (int off = 16; off <= 32; off <<= 1) {
            a4.x += __shfl_xor(a4.x, off);
            a4.y += __shfl_xor(a4.y, off);
            a4.z += __shfl_xor(a4.z, off);
            a4.w += __shfl_xor(a4.w, off);
            ps   += __shfl_xor(ps,   off);
        }
        if (g == 0) {
            float rh = 1.f / (ps + 1e-16f);
            float4 bb = *(const float4*)&b1[j * 4];
            float4 o;
            o.x = fmaxf(a4.x * rh + bb.x, 0.f);
            o.y = fmaxf(a4.y * rh + bb.y, 0.f);
            o.z = fmaxf(a4.z * rh + bb.z, 0.f);
            o.w = fmaxf(a4.w * rh + bb.w, 0.f);
            *(float4*)&out1[(size_t)n * 64 + j * 4] = o;
        }
    } else {
        // fallback deg>DCAP: first DCAP slots in csrF + matching overflow entries
        int h = lane >> 4;
        int oN = min(*ovfcnt, MAXOVF);
        float s0 = 0.f, s1 = 0.f, s2 = 0.f, s3 = 0.f;
        for (int i = lane; i < DCAP; i += 64) {
            int s = cf[i];
            float4 a = *(const float4*)(als + 4 * s);
            s0 += __expf(lrelu(a.x + ald.x));
            s1 += __expf(lrelu(a.y + ald.y));
            s2 += __expf(lrelu(a.z + ald.z));
            s3 += __expf(lrelu(a.w + ald.w));
        }
        for (int i = lane; i < oN; i += 64) {
            int2 pr = ovf[i];
            if (pr.y == n) {
                float4 a = *(const float4*)(als + 4 * pr.x);
                s0 += __expf(lrelu(a.x + ald.x));
                s1 += __expf(lrelu(a.y + ald.y));
                s2 += __expf(lrelu(a.z + ald.z));
                s3 += __expf(lrelu(a.w + ald.w));
            }
        }
        #pragma unroll
        for (int off = 32; off; off >>= 1) {
            s0 += __shfl_xor(s0, off);
            s1 += __shfl_xor(s1, off);
            s2 += __shfl_xor(s2, off);
            s3 += __shfl_xor(s3, off);
        }
        float sh = (h == 0) ? s0 : (h == 1) ? s1 : (h == 2) ? s2 : s3;
        float ah = (h == 0) ? ald.x : (h == 1) ? ald.y : (h == 2) ? ald.z : ald.w;
        float rh = 1.f / (sh + 1e-16f);
        float acc = 0.f;
        for (int e = 0; e < DCAP; ++e) {
            int s = cf[e];
            float av = als[4 * s + h];
            float ph = __expf(lrelu(av + ah));
            acc = fmaf(ph, bf2f(h1b[(size_t)s * 64 + lane]), acc);
        }
        for (int o = 0; o < oN; ++o) {
            int2 pr = ovf[o];
            if (pr.y == n) {
                float av = als[4 * pr.x + h];
                float ph = __expf(lrelu(av + ah));
                acc = fmaf(ph, bf2f(h1b[(size_t)pr.x * 64 + lane]), acc);
            }
        }
        out1[(size_t)n * 64 + lane] = fmaxf(acc * rh + b1[lane], 0.f);
    }
}

// ---------- GEMM2 + fused al2: h2b[N,32](bf16) = out1[N,64]@W2 ----------
// fp32 W; unroll capped at 2 to avoid R13's 256-VGPR full-unroll cliff
__global__ __launch_bounds__(256) void k_gemm2(const float* __restrict__ in,
                                               const float* __restrict__ Wf,
                                               const float* __restrict__ asf_p,
                                               const float* __restrict__ adf_p,
                                               unsigned short* __restrict__ h2b,
                                               float* __restrict__ als, float* __restrict__ ald) {
    __shared__ float Wt[32 * 65];    // stride 65: conflict-free b32 reads
    __shared__ float xt[64 * 68];
    int tid = threadIdx.x;
    int rb = blockIdx.x * 64;
    for (int i = tid; i < 64 * 32; i += 256) {
        int k = i >> 5, c = i & 31;
        Wt[c * 65 + k] = Wf[i];
    }
    for (int i = tid; i < 64 * 16; i += 256) {
        int r = i >> 4, kq = i & 15;
        float4 v = make_float4(0.f, 0.f, 0.f, 0.f);
        if (rb + r < NN) v = ((const float4*)in)[(size_t)(rb + r) * 16 + kq];
        *(float4*)&xt[r * 68 + kq * 4] = v;
    }
    __syncthreads();
    int c = tid & 31, rg = tid >> 5;
    float acc[8];
    #pragma unroll
    for (int j = 0; j < 8; j++) acc[j] = 0.f;
    #pragma unroll 2
    for (int k = 0; k < 64; k += 4) {
        float4 w;
        w.x = Wt[c * 65 + k];     w.y = Wt[c * 65 + k + 1];
        w.z = Wt[c * 65 + k + 2]; w.w = Wt[c * 65 + k + 3];
        #pragma unroll
        for (int j = 0; j < 8; j++) {
            float4 xv = *(const float4*)&xt[(rg * 8 + j) * 68 + k];
            acc[j] = fmaf(xv.x, w.x, fmaf(xv.y, w.y, fmaf(xv.z, w.z, fmaf(xv.w, w.w, acc[j]))));
        }
    }
    float asf = asf_p[c], adf = adf_p[c];
    #pragma unroll
    for (int j = 0; j < 8; j++) {
        int r = rb + rg * 8 + j;
        bool ok = r < NN;
        if (ok) h2b[(size_t)r * 32 + c] = f2bf(acc[j]);
        float v = acc[j] * asf, w = acc[j] * adf;
        #pragma unroll
        for (int off = 1; off < 8; off <<= 1) {
            v += __shfl_xor(v, off);
            w += __shfl_xor(w, off);
        }
        if (ok && (c & 7) == 0) {
            als[r * 4 + (c >> 3)] = v;
            ald[r * 4 + (c >> 3)] = w;
        }
    }
}

// ---------- layer-2 aggregation + log_softmax: wave/node; sum folded into phase C ----------
__global__ __launch_bounds__(256) void k_agg2(const int* __restrict__ degv, const unsigned short* __restrict__ csrF,
                                              const int2* __restrict__ ovf, const int* __restrict__ ovfcnt,
                                              const float* __restrict__ als, const float* __restrict__ aldv,
                                              const unsigned short* __restrict__ h2b,
                                              const float* __restrict__ b2,
                                              float* __restrict__ out) {
    __shared__ float pv[4][DCAP * 4];
    __shared__ int  sidx[4][DCAP];
    int w = threadIdx.x >> 6, lane = threadIdx.x & 63;
    int n = blockIdx.x * 4 + w;
    if (n >= NN) return;
    int dg = degv[n];
    const unsigned short* cf = csrF + (size_t)n * DCAP;
    float4 ald = *(const float4*)(aldv + 4 * n);

    if (dg <= DCAP) {
        int sA = 0;
        bool v0 = lane < dg;
        if (v0) {
            sA = cf[lane];
            sidx[w][lane] = sA;
            float4 a = *(const float4*)(als + 4 * sA);
            float4 p;
            p.x = __expf(lrelu(a.x + ald.x)); p.y = __expf(lrelu(a.y + ald.y));
            p.z = __expf(lrelu(a.z + ald.z)); p.w = __expf(lrelu(a.w + ald.w));
            *(float4*)&pv[w][lane * 4] = p;
        }
        int degp = (dg + 7) & ~7;
        int s0v = __shfl(sA, 0);
        if (lane >= dg && lane < degp) {
            sidx[w][lane] = s0v;
            *(float4*)&pv[w][lane * 4] = make_float4(0.f, 0.f, 0.f, 0.f);
        }
        // phase C: 8 lane-groups x 8 lanes; lane owns channels j*4..j*4+3 (bf16 uint2)
        int g = lane >> 3, j = lane & 7, hh = j >> 1;
        float4 a4 = make_float4(0.f, 0.f, 0.f, 0.f);
        float ps = 0.f;
        for (int e = 0; e < degp; e += 8) {
            int s = sidx[w][e + g];
            float ph = pv[w][(e + g) * 4 + hh];
            uint2 rv = *(const uint2*)&h2b[(size_t)s * 32 + j * 4];
            ps += ph;
            a4.x = fmaf(ph, bf2f((unsigned short)(rv.x & 0xffff)), a4.x);
            a4.y = fmaf(ph, bf2f((unsigned short)(rv.x >> 16)),    a4.y);
            a4.z = fmaf(ph, bf2f((unsigned short)(rv.y & 0xffff)), a4.z);
            a4.w = fmaf(ph, bf2f((unsigned short)(rv.y >> 16)),    a4.w);
        }
        #pragma unroll
        for (int off = 8; off <= 32; off <<= 1) {
            a4.x += __shfl_xor(a4.x, off);
            a4.y += __shfl_xor(a4.y, off);
            a4.z += __shfl_xor(a4.z, off);
            a4.w += __shfl_xor(a4.w, off);
            ps   += __shfl_xor(ps,   off);
        }
        float rh = 1.f / (ps + 1e-16f);
        float4 bb = *(const float4*)&b2[j * 4];
        float4 row;
        row.x = a4.x * rh + bb.x; row.y = a4.y * rh + bb.y;
        row.z = a4.z * rh + bb.z; row.w = a4.w * rh + bb.w;
        // log_softmax over 32 channels: reduce within 8-lane channel group
        float mx = fmaxf(fmaxf(row.x, row.y), fmaxf(row.z, row.w));
        #pragma unroll
        for (int off = 1; off < 8; off <<= 1) mx = fmaxf(mx, __shfl_xor(mx, off));
        float sm = __expf(row.x - mx) + __expf(row.y - mx)
                 + __expf(row.z - mx) + __expf(row.w - mx);
        #pragma unroll
        for (int off = 1; off < 8; off <<= 1) sm += __shfl_xor(sm, off);
        float lse = mx + logf(sm);
        if (g == 0) {
            float4 o;
            o.x = row.x - lse; o.y = row.y - lse;
            o.z = row.z - lse; o.w = row.w - lse;
            *(float4*)&out[(size_t)n * 32 + j * 4] = o;
        }
    } else {
        // fallback deg>DCAP: first DCAP slots + matching overflow entries
        int oN = min(*ovfcnt, MAXOVF);
        float s0 = 0.f, s1 = 0.f, s2 = 0.f, s3 = 0.f;
        for (int i = lane; i < DCAP; i += 64) {
            int s = cf[i];
            float4 a = *(const float4*)(als + 4 * s);
            s0 += __expf(lrelu(a.x + ald.x));
            s1 += __expf(lrelu(a.y + ald.y));
            s2 += __expf(lrelu(a.z + ald.z));
            s3 += __expf(lrelu(a.w + ald.w));
        }
        for (int i = lane; i < oN; i += 64) {
            int2 pr = ovf[i];
            if (pr.y == n) {
                float4 a = *(const float4*)(als + 4 * pr.x);
                s0 += __expf(lrelu(a.x + ald.x));
                s1 += __expf(lrelu(a.y + ald.y));
                s2 += __expf(lrelu(a.z + ald.z));
                s3 += __expf(lrelu(a.w + ald.w));
            }
        }
        #pragma unroll
        for (int off = 32; off; off >>= 1) {
            s0 += __shfl_xor(s0, off);
            s1 += __shfl_xor(s1, off);
            s2 += __shfl_xor(s2, off);
            s3 += __shfl_xor(s3, off);
        }
        int L = lane & 31;
        int h2i = L >> 3;
        float sh2 = (h2i == 0) ? s0 : (h2i == 1) ? s1 : (h2i == 2) ? s2 : s3;
        float ah2 = (h2i == 0) ? ald.x : (h2i == 1) ? ald.y : (h2i == 2) ? ald.z : ald.w;
        float rh2 = 1.f / (sh2 + 1e-16f);
        if (lane < 32) {
            float acc = 0.f;
            for (int e = 0; e < DCAP; ++e) {
                int s = cf[e];
                float av = als[4 * s + h2i];
                float ph = __expf(lrelu(av + ah2));
                acc = fmaf(ph, bf2f(h2b[(size_t)s * 32 + L]), acc);
            }
            for (int o = 0; o < oN; ++o) {
                int2 pr = ovf[o];
                if (pr.y == n) {
                    float av = als[4 * pr.x + h2i];
                    float ph = __expf(lrelu(av + ah2));
                    acc = fmaf(ph, bf2f(h2b[(size_t)pr.x * 32 + L]), acc);
                }
            }
            float row = acc * rh2 + b2[L];
            float mx = row;
            #pragma unroll
            for (int off = 16; off; off >>= 1) mx = fmaxf(mx, __shfl_xor(mx, off, 32));
            float pe = __expf(row - mx);
            float sm = pe;
            #pragma unroll
            for (int off = 16; off; off >>= 1) sm += __shfl_xor(sm, off, 32);
            out[(size_t)n * 32 + L] = row - mx - logf(sm);
        }
    }
}

extern "C" void kernel_launch(void* const* d_in, const int* in_sizes, int n_in,
                              void* d_out, int out_size, void* d_ws, size_t ws_size,
                              hipStream_t stream) {
    const void* x  = d_in[0];
    const void* ei = d_in[1];
    float* out = (float*)d_out;

    char* p = (char*)d_ws;
    auto take = [&](size_t b) -> char* {
        char* r = p; p += (b + 255) & ~(size_t)255; return r;
    };
    int*   ovfcnt = (int*)take(sizeof(int) * 8);
    int*   deg   = (int*)take(sizeof(int) * NN);
    unsigned short* csrF = (unsigned short*)take(sizeof(unsigned short) * (size_t)NNP * DCAP);
    int2*  ovf   = (int2*)take(sizeof(int2) * MAXOVF);
    unsigned int* pk = (unsigned int*)take(sizeof(unsigned int) * ET);
    float* wsm   = (float*)take(sizeof(float) * 10528);
    unsigned short* h1b = (unsigned short*)take(sizeof(unsigned short) * (size_t)NN * 64);
    float* als1  = (float*)take(sizeof(float) * NN * 4);
    float* ald1  = (float*)take(sizeof(float) * NN * 4);
    float* out1  = (float*)take(sizeof(float) * (size_t)NN * 64);
    unsigned short* h2b = (unsigned short*)take(sizeof(unsigned short) * (size_t)NN * 32);
    float* als2  = (float*)take(sizeof(float) * NN * 4);
    float* ald2  = (float*)take(sizeof(float) * NN * 4);

    float* Wf2  = wsm + 8384;
    float* as2f = wsm + 10432;
    float* ad2f = wsm + 10464;
    float* b1f  = wsm + 8320;
    float* b2f  = wsm + 10496;

    hipMemsetAsync(ovfcnt, 0, sizeof(int) * 8, stream);
    k_compact<<<NCB, 256, 0, stream>>>(x, ei, d_in[2], d_in[3], d_in[4], d_in[5],
                                       d_in[6], d_in[7], d_in[8], d_in[9],
                                       pk, wsm);
    k_front<<<NFB, 256, 0, stream>>>(x, d_in[2], d_in[3], d_in[4], pk,
                                     h1b, als1, ald1, csrF, deg, ovf, ovfcnt);
    k_agg1<<<(NN + 3) / 4, 256, 0, stream>>>(deg, csrF, ovf, ovfcnt, als1, ald1, h1b, b1f, out1);
    k_gemm2<<<(NN + 63) / 64, 256, 0, stream>>>(out1, Wf2, as2f, ad2f, h2b, als2, ald2);
    k_agg2<<<(NN + 3) / 4, 256, 0, stream>>>(deg, csrF, ovf, ovfcnt, als2, ald2, h2b, b2f, out);
}

// Round 13
// 221.066 us; speedup vs baseline: 4.7427x; 4.7427x over previous
//
#include <hip/hip_runtime.h>
#include <hip/hip_bf16.h>
#include <math.h>

#define NN 50000
#define NE 800000
#define ET (NE + NN)
#define DCAP 48        // fixed CSR slot capacity per node (Poisson(17) tail: P(deg>=48)~2e-9)
#define MAXOVF 8192    // overflow capacity (expected 0 used; correctness via fallback scan)
#define NG1R 1568      // fused front grid: 8*196 (uniform 196 blocks per partition)
#define NBP 196        // covering blocks per partition
#define NRANGE 6250    // NN/8: dst-nodes per partition

__device__ __forceinline__ float bf2f(unsigned short u) {
    return __uint_as_float(((unsigned)u) << 16);
}
__device__ __forceinline__ unsigned short f2bf(float f) {   // RNE
    unsigned u = __float_as_uint(f);
    return (unsigned short)((u + 0x7fff + ((u >> 16) & 1)) >> 16);
}
__device__ __forceinline__ float lrelu(float e) {
    return e >= 0.f ? e : 0.2f * e;
}

// ---------- fused front: GEMM1 + al1 + partitioned direct-slot CSR build ----------
// R8-verified best (221.5us). Partitioned tail (8 passes) + ushort csrF rows.
// NOTE (R9-R12): scattered csrF writes have a ~38MB floor from 8-XCD line
// writeback; single-writer binning (R12) fixes WRITE (12.7MB) but destroys scan
// parallelism (196 serial blocks -> 900us). This structure is the measured optimum.
__global__ __launch_bounds__(256) void k_gemm1cv(const void* __restrict__ xraw,
                                                 const void* __restrict__ ei,
                                                 const void* p2, const void* p3, const void* p4, const void* p5,
                                                 const void* p6, const void* p7, const void* p8, const void* p9,
                                                 unsigned short* __restrict__ h1b,
                                                 float* __restrict__ als, float* __restrict__ ald,
                                                 unsigned short* __restrict__ csrF, int* __restrict__ deg,
                                                 int2* __restrict__ ovf, int* __restrict__ ovfcnt,
                                                 float* __restrict__ wsm) {
    __shared__ unsigned int Wp[64 * 65]; // Wp[c][k2], 2 bf16/elem; bank (c+k2)%32 conflict-free
    __shared__ float xt[32 * 132];       // fp32, b128-aligned, broadcast reads
    __shared__ int wred[8];              // dtype-detect reduce
    int tid = threadIdx.x;
    int rb = blockIdx.x * 32;

    // --- per-block dtype detection (1024-elem L2-broadcast windows) ---
    const unsigned long long* e64u = (const unsigned long long*)ei;
    const unsigned int* x32 = (const unsigned int*)xraw;
    int ci = 0, cf = 0;
    #pragma unroll
    for (int q = 0; q < 4; q++) {
        if (e64u[4 * tid + q] >= (unsigned long long)NN) ci = 1;
        unsigned ex = (x32[4 * tid + q] >> 7) & 0xFFu;
        cf += (ex >= 96 && ex <= 140) ? 1 : 0;
    }
    #pragma unroll
    for (int off = 32; off; off >>= 1) { ci |= __shfl_xor(ci, off); cf += __shfl_xor(cf, off); }
    if ((tid & 63) == 0) { wred[tid >> 6] = ci; wred[4 + (tid >> 6)] = cf; }
    __syncthreads();
    int iflag = (wred[0] | wred[1] | wred[2] | wred[3]) ? 0 : 1;  // 1 = int64
    int fl = ((wred[4] + wred[5] + wred[6] + wred[7]) > 700) ? 1 : 0;  // 1 = bf16

    if (rb < NN) {   // ===== gemm phase (block-uniform branch; tail-pad blocks skip) =====
        const void* w1raw = p2; const void* as1raw = p3; const void* ad1raw = p4;
        for (int i = tid; i < 64 * 64; i += 256) {
            int k2 = i >> 6, c = i & 63;     // k2 = k/2
            unsigned lo, hi;
            if (fl) {
                lo = ((const unsigned short*)w1raw)[(2 * k2) * 64 + c];
                hi = ((const unsigned short*)w1raw)[(2 * k2 + 1) * 64 + c];
            } else {
                lo = f2bf(((const float*)w1raw)[(2 * k2) * 64 + c]);
                hi = f2bf(((const float*)w1raw)[(2 * k2 + 1) * 64 + c]);
            }
            Wp[c * 65 + k2] = lo | (hi << 16);
        }
        if (fl) {   // bf16 input
            const unsigned short* xb = (const unsigned short*)xraw;
            for (int i = tid; i < 32 * 16; i += 256) {
                int r = i >> 4, k8 = i & 15;
                float f[8];
                if (rb + r < NN) {
                    uint4 v = ((const uint4*)xb)[(size_t)(rb + r) * 16 + k8];
                    f[0] = bf2f((unsigned short)(v.x & 0xffff)); f[1] = bf2f((unsigned short)(v.x >> 16));
                    f[2] = bf2f((unsigned short)(v.y & 0xffff)); f[3] = bf2f((unsigned short)(v.y >> 16));
                    f[4] = bf2f((unsigned short)(v.z & 0xffff)); f[5] = bf2f((unsigned short)(v.z >> 16));
                    f[6] = bf2f((unsigned short)(v.w & 0xffff)); f[7] = bf2f((unsigned short)(v.w >> 16));
                } else {
                    #pragma unroll
                    for (int q = 0; q < 8; q++) f[q] = 0.f;
                }
                int o = r * 132 + k8 * 8;
                *(float4*)&xt[o]     = make_float4(f[0], f[1], f[2], f[3]);
                *(float4*)&xt[o + 4] = make_float4(f[4], f[5], f[6], f[7]);
            }
        } else {    // fp32 input
            const float* xf = (const float*)xraw;
            for (int i = tid; i < 32 * 32; i += 256) {
                int r = i >> 5, kq = i & 31;
                float4 v = make_float4(0.f, 0.f, 0.f, 0.f);
                if (rb + r < NN) v = ((const float4*)xf)[(size_t)(rb + r) * 32 + kq];
                *(float4*)&xt[r * 132 + kq * 4] = v;
            }
        }
        __syncthreads();
        int c = tid & 63;
        int rg = tid >> 6;
        float acc[8];
        #pragma unroll
        for (int j = 0; j < 8; j++) acc[j] = 0.f;
        for (int k2 = 0; k2 < 64; k2 += 2) {     // 4 k-values per iteration
            unsigned q0 = Wp[c * 65 + k2];
            unsigned q1 = Wp[c * 65 + k2 + 1];
            float w0 = __uint_as_float(q0 << 16);
            float w1 = __uint_as_float(q0 & 0xffff0000u);
            float w2 = __uint_as_float(q1 << 16);
            float w3 = __uint_as_float(q1 & 0xffff0000u);
            int kk = k2 * 2;
            #pragma unroll
            for (int j = 0; j < 8; j++) {
                float4 xv = *(const float4*)&xt[(rg * 8 + j) * 132 + kk];
                acc[j] = fmaf(xv.x, w0, fmaf(xv.y, w1, fmaf(xv.z, w2, fmaf(xv.w, w3, acc[j]))));
            }
        }
        float asf = fl ? bf2f(((const unsigned short*)as1raw)[c]) : ((const float*)as1raw)[c];
        float adf = fl ? bf2f(((const unsigned short*)ad1raw)[c]) : ((const float*)ad1raw)[c];
        #pragma unroll
        for (int j = 0; j < 8; j++) {
            int r = rb + rg * 8 + j;
            bool ok = r < NN;
            if (ok) h1b[(size_t)r * 64 + c] = f2bf(acc[j]);
            float v = acc[j] * asf, w = acc[j] * adf;
            #pragma unroll
            for (int off = 1; off < 16; off <<= 1) {
                v += __shfl_xor(v, off);
                w += __shfl_xor(w, off);
            }
            if (ok && (c & 15) == 0) {
                als[r * 4 + (c >> 4)] = v;
                ald[r * 4 + (c >> 4)] = w;
            }
        }
    }

    // ===== small-weight convert (single covering: blocks 0..41) =====
    int ew = blockIdx.x * 256 + tid;
    if (ew < 10528) {
        const void* p; int off;
        if (ew < 8192)       { p = p2; off = ew; }
        else if (ew < 8256)  { p = p3; off = ew - 8192; }
        else if (ew < 8320)  { p = p4; off = ew - 8256; }
        else if (ew < 8384)  { p = p5; off = ew - 8320; }
        else if (ew < 10432) { p = p6; off = ew - 8384; }
        else if (ew < 10464) { p = p7; off = ew - 10432; }
        else if (ew < 10496) { p = p8; off = ew - 10464; }
        else                 { p = p9; off = ew - 10496; }
        wsm[ew] = fl ? bf2f(((const unsigned short*)p)[off]) : ((const float*)p)[off];
    }

    // ===== partitioned CSR tail =====
    int part = blockIdx.x & 7;
    int bi = blockIdx.x >> 3;           // 0..195 within partition
    int lo = part * NRANGE, hi = lo + NRANGE;
    const long long* e64s = (const long long*)ei;
    const int* e32s = (const int*)ei;
    for (int e = bi * 256 + tid; e < ET; e += NBP * 256) {
        int d;
        if (e >= NE) d = e - NE;                       // self-loops
        else if (iflag) d = (int)e64s[NE + e];
        else d = e32s[NE + e];
        if (d >= lo && d < hi) {
            int s;
            if (e >= NE) s = d;
            else if (iflag) s = (int)e64s[e];
            else s = e32s[e];
            int slot = atomicAdd(&deg[d], 1);
            if (slot < DCAP) csrF[(size_t)d * DCAP + slot] = (unsigned short)s;
            else {
                int o = atomicAdd(ovfcnt, 1);
                if (o < MAXOVF) ovf[o] = make_int2(s, d);
            }
        }
    }
}

// ---------- layer-1 aggregation: wave/node; no-max softmax; sum folded into phase C ----------
// |logit| <= ~6 by range analysis -> exp() safe in fp32 without max-shift
__global__ __launch_bounds__(256) void k_agg1(const int* __restrict__ degv, const unsigned short* __restrict__ csrF,
                                              const int2* __restrict__ ovf, const int* __restrict__ ovfcnt,
                                              const float* __restrict__ als, const float* __restrict__ aldv,
                                              const unsigned short* __restrict__ h1b,
                                              const float* __restrict__ b1,
                                              float* __restrict__ out1) {
    __shared__ float pv[4][DCAP * 4];
    __shared__ int  sidx[4][DCAP];
    int w = threadIdx.x >> 6, lane = threadIdx.x & 63;
    int n = blockIdx.x * 4 + w;
    if (n >= NN) return;
    int dg = degv[n];
    const unsigned short* cf = csrF + (size_t)n * DCAP;
    float4 ald = *(const float4*)(aldv + 4 * n);

    if (dg <= DCAP) {
        int sA = 0;
        bool v0 = lane < dg;
        // phase A: compute exp(lrelu(logit)) per edge, store to LDS (no reduction)
        if (v0) {
            sA = cf[lane];
            sidx[w][lane] = sA;
            float4 a = *(const float4*)(als + 4 * sA);
            float4 p;
            p.x = __expf(lrelu(a.x + ald.x)); p.y = __expf(lrelu(a.y + ald.y));
            p.z = __expf(lrelu(a.z + ald.z)); p.w = __expf(lrelu(a.w + ald.w));
            *(float4*)&pv[w][lane * 4] = p;
        }
        // pad to multiple of 4 with zero-weight entries pointing at a valid row
        int degp = (dg + 3) & ~3;
        int s0v = __shfl(sA, 0);
        if (lane >= dg && lane < degp) {
            sidx[w][lane] = s0v;
            *(float4*)&pv[w][lane * 4] = make_float4(0.f, 0.f, 0.f, 0.f);
        }
        // phase C: 4 lane-groups x 16 lanes; lane owns channels j*4..j*4+3 (bf16 uint2)
        // softmax denominator folded in: ps accumulates this lane's head-p per edge
        int g = lane >> 4, j = lane & 15, hh = j >> 2;
        float4 a4 = make_float4(0.f, 0.f, 0.f, 0.f);
        float ps = 0.f;
        for (int e = 0; e < degp; e += 4) {
            int s = sidx[w][e + g];
            float ph = pv[w][(e + g) * 4 + hh];
            uint2 rv = *(const uint2*)&h1b[(size_t)s * 64 + j * 4];
            ps += ph;
            a4.x = fmaf(ph, bf2f((unsigned short)(rv.x & 0xffff)), a4.x);
            a4.y = fmaf(ph, bf2f((unsigned short)(rv.x >> 16)),    a4.y);
            a4.z = fmaf(ph, bf2f((unsigned short)(rv.y & 0xffff)), a4.z);
            a4.w = fmaf(ph, bf2f((unsigned short)(rv.y >> 16)),    a4.w);
        }
        #pragma unroll
        for (int off = 16; off <= 32; off <<= 1) {
            a4.x += __shfl_xor(a4.x, off);
            a4.y += __shfl_xor(a4.y, off);
            a4.z += __shfl_xor(a4.z, off);
            a4.w += __shfl_xor(a4.w, off);
            ps   += __shfl_xor(ps,   off);
        }
        if (g == 0) {
            float rh = 1.f / (ps + 1e-16f);
            float4 bb = *(const float4*)&b1[j * 4];
            float4 o;
            o.x = fmaxf(a4.x * rh + bb.x, 0.f);
            o.y = fmaxf(a4.y * rh + bb.y, 0.f);
            o.z = fmaxf(a4.z * rh + bb.z, 0.f);
            o.w = fmaxf(a4.w * rh + bb.w, 0.f);
            *(float4*)&out1[(size_t)n * 64 + j * 4] = o;
        }
    } else {
        // fallback deg>DCAP: first DCAP slots in csrF + matching overflow entries
        int h = lane >> 4;
        int oN = min(*ovfcnt, MAXOVF);
        float s0 = 0.f, s1 = 0.f, s2 = 0.f, s3 = 0.f;
        for (int i = lane; i < DCAP; i += 64) {
            int s = cf[i];
            float4 a = *(const float4*)(als + 4 * s);
            s0 += __expf(lrelu(a.x + ald.x));
            s1 += __expf(lrelu(a.y + ald.y));
            s2 += __expf(lrelu(a.z + ald.z));
            s3 += __expf(lrelu(a.w + ald.w));
        }
        for (int i = lane; i < oN; i += 64) {
            int2 pr = ovf[i];
            if (pr.y == n) {
                float4 a = *(const float4*)(als + 4 * pr.x);
                s0 += __expf(lrelu(a.x + ald.x));
                s1 += __expf(lrelu(a.y + ald.y));
                s2 += __expf(lrelu(a.z + ald.z));
                s3 += __expf(lrelu(a.w + ald.w));
            }
        }
        #pragma unroll
        for (int off = 32; off; off >>= 1) {
            s0 += __shfl_xor(s0, off);
            s1 += __shfl_xor(s1, off);
            s2 += __shfl_xor(s2, off);
            s3 += __shfl_xor(s3, off);
        }
        float sh = (h == 0) ? s0 : (h == 1) ? s1 : (h == 2) ? s2 : s3;
        float ah = (h == 0) ? ald.x : (h == 1) ? ald.y : (h == 2) ? ald.z : ald.w;
        float rh = 1.f / (sh + 1e-16f);
        float acc = 0.f;
        for (int e = 0; e < DCAP; ++e) {
            int s = cf[e];
            float av = als[4 * s + h];
            float ph = __expf(lrelu(av + ah));
            acc = fmaf(ph, bf2f(h1b[(size_t)s * 64 + lane]), acc);
        }
        for (int o = 0; o < oN; ++o) {
            int2 pr = ovf[o];
            if (pr.y == n) {
                float av = als[4 * pr.x + h];
                float ph = __expf(lrelu(av + ah));
                acc = fmaf(ph, bf2f(h1b[(size_t)pr.x * 64 + lane]), acc);
            }
        }
        out1[(size_t)n * 64 + lane] = fmaxf(acc * rh + b1[lane], 0.f);
    }
}

// ---------- GEMM2 + fused al2: h2b[N,32](bf16) = out1[N,64]@W2 ----------
// fp32 W; unroll capped at 2 to avoid R13's 256-VGPR full-unroll cliff
__global__ __launch_bounds__(256) void k_gemm2(const float* __restrict__ in,
                                               const float* __restrict__ Wf,
                                               const float* __restrict__ asf_p,
                                               const float* __restrict__ adf_p,
                                               unsigned short* __restrict__ h2b,
                                               float* __restrict__ als, float* __restrict__ ald) {
    __shared__ float Wt[32 * 65];    // stride 65: conflict-free b32 reads
    __shared__ float xt[64 * 68];
    int tid = threadIdx.x;
    int rb = blockIdx.x * 64;
    for (int i = tid; i < 64 * 32; i += 256) {
        int k = i >> 5, c = i & 31;
        Wt[c * 65 + k] = Wf[i];
    }
    for (int i = tid; i < 64 * 16; i += 256) {
        int r = i >> 4, kq = i & 15;
        float4 v = make_float4(0.f, 0.f, 0.f, 0.f);
        if (rb + r < NN) v = ((const float4*)in)[(size_t)(rb + r) * 16 + kq];
        *(float4*)&xt[r * 68 + kq * 4] = v;
    }
    __syncthreads();
    int c = tid & 31, rg = tid >> 5;
    float acc[8];
    #pragma unroll
    for (int j = 0; j < 8; j++) acc[j] = 0.f;
    #pragma unroll 2
    for (int k = 0; k < 64; k += 4) {
        float4 w;
        w.x = Wt[c * 65 + k];     w.y = Wt[c * 65 + k + 1];
        w.z = Wt[c * 65 + k + 2]; w.w = Wt[c * 65 + k + 3];
        #pragma unroll
        for (int j = 0; j < 8; j++) {
            float4 xv = *(const float4*)&xt[(rg * 8 + j) * 68 + k];
            acc[j] = fmaf(xv.x, w.x, fmaf(xv.y, w.y, fmaf(xv.z, w.z, fmaf(xv.w, w.w, acc[j]))));
        }
    }
    float asf = asf_p[c], adf = adf_p[c];
    #pragma unroll
    for (int j = 0; j < 8; j++) {
        int r = rb + rg * 8 + j;
        bool ok = r < NN;
        if (ok) h2b[(size_t)r * 32 + c] = f2bf(acc[j]);
        float v = acc[j] * asf, w = acc[j] * adf;
        #pragma unroll
        for (int off = 1; off < 8; off <<= 1) {
            v += __shfl_xor(v, off);
            w += __shfl_xor(w, off);
        }
        if (ok && (c & 7) == 0) {
            als[r * 4 + (c >> 3)] = v;
            ald[r * 4 + (c >> 3)] = w;
        }
    }
}

// ---------- layer-2 aggregation + log_softmax: wave/node; sum folded into phase C ----------
__global__ __launch_bounds__(256) void k_agg2(const int* __restrict__ degv, const unsigned short* __restrict__ csrF,
                                              const int2* __restrict__ ovf, const int* __restrict__ ovfcnt,
                                              const float* __restrict__ als, const float* __restrict__ aldv,
                                              const unsigned short* __restrict__ h2b,
                                              const float* __restrict__ b2,
                                              float* __restrict__ out) {
    __shared__ float pv[4][DCAP * 4];
    __shared__ int  sidx[4][DCAP];
    int w = threadIdx.x >> 6, lane = threadIdx.x & 63;
    int n = blockIdx.x * 4 + w;
    if (n >= NN) return;
    int dg = degv[n];
    const unsigned short* cf = csrF + (size_t)n * DCAP;
    float4 ald = *(const float4*)(aldv + 4 * n);

    if (dg <= DCAP) {
        int sA = 0;
        bool v0 = lane < dg;
        if (v0) {
            sA = cf[lane];
            sidx[w][lane] = sA;
            float4 a = *(const float4*)(als + 4 * sA);
            float4 p;
            p.x = __expf(lrelu(a.x + ald.x)); p.y = __expf(lrelu(a.y + ald.y));
            p.z = __expf(lrelu(a.z + ald.z)); p.w = __expf(lrelu(a.w + ald.w));
            *(float4*)&pv[w][lane * 4] = p;
        }
        int degp = (dg + 7) & ~7;
        int s0v = __shfl(sA, 0);
        if (lane >= dg && lane < degp) {
            sidx[w][lane] = s0v;
            *(float4*)&pv[w][lane * 4] = make_float4(0.f, 0.f, 0.f, 0.f);
        }
        // phase C: 8 lane-groups x 8 lanes; lane owns channels j*4..j*4+3 (bf16 uint2)
        int g = lane >> 3, j = lane & 7, hh = j >> 1;
        float4 a4 = make_float4(0.f, 0.f, 0.f, 0.f);
        float ps = 0.f;
        for (int e = 0; e < degp; e += 8) {
            int s = sidx[w][e + g];
            float ph = pv[w][(e + g) * 4 + hh];
            uint2 rv = *(const uint2*)&h2b[(size_t)s * 32 + j * 4];
            ps += ph;
            a4.x = fmaf(ph, bf2f((unsigned short)(rv.x & 0xffff)), a4.x);
            a4.y = fmaf(ph, bf2f((unsigned short)(rv.x >> 16)),    a4.y);
            a4.z = fmaf(ph, bf2f((unsigned short)(rv.y & 0xffff)), a4.z);
            a4.w = fmaf(ph, bf2f((unsigned short)(rv.y >> 16)),    a4.w);
        }
        #pragma unroll
        for (int off = 8; off <= 32; off <<= 1) {
            a4.x += __shfl_xor(a4.x, off);
            a4.y += __shfl_xor(a4.y, off);
            a4.z += __shfl_xor(a4.z, off);
            a4.w += __shfl_xor(a4.w, off);
            ps   += __shfl_xor(ps,   off);
        }
        float rh = 1.f / (ps + 1e-16f);
        float4 bb = *(const float4*)&b2[j * 4];
        float4 row;
        row.x = a4.x * rh + bb.x; row.y = a4.y * rh + bb.y;
        row.z = a4.z * rh + bb.z; row.w = a4.w * rh + bb.w;
        // log_softmax over 32 channels: reduce within 8-lane channel group
        float mx = fmaxf(fmaxf(row.x, row.y), fmaxf(row.z, row.w));
        #pragma unroll
        for (int off = 1; off < 8; off <<= 1) mx = fmaxf(mx, __shfl_xor(mx, off));
        float sm = __expf(row.x - mx) + __expf(row.y - mx)
                 + __expf(row.z - mx) + __expf(row.w - mx);
        #pragma unroll
        for (int off = 1; off < 8; off <<= 1) sm += __shfl_xor(sm, off);
        float lse = mx + logf(sm);
        if (g == 0) {
            float4 o;
            o.x = row.x - lse; o.y = row.y - lse;
            o.z = row.z - lse; o.w = row.w - lse;
            *(float4*)&out[(size_t)n * 32 + j * 4] = o;
        }
    } else {
        // fallback deg>DCAP: first DCAP slots + matching overflow entries
        int oN = min(*ovfcnt, MAXOVF);
        float s0 = 0.f, s1 = 0.f, s2 = 0.f, s3 = 0.f;
        for (int i = lane; i < DCAP; i += 64) {
            int s = cf[i];
            float4 a = *(const float4*)(als + 4 * s);
            s0 += __expf(lrelu(a.x + ald.x));
            s1 += __expf(lrelu(a.y + ald.y));
            s2 += __expf(lrelu(a.z + ald.z));
            s3 += __expf(lrelu(a.w + ald.w));
        }
        for (int i = lane; i < oN; i += 64) {
            int2 pr = ovf[i];
            if (pr.y == n) {
                float4 a = *(const float4*)(als + 4 * pr.x);
                s0 += __expf(lrelu(a.x + ald.x));
                s1 += __expf(lrelu(a.y + ald.y));
                s2 += __expf(lrelu(a.z + ald.z));
                s3 += __expf(lrelu(a.w + ald.w));
            }
        }
        #pragma unroll
        for (int off = 32; off; off >>= 1) {
            s0 += __shfl_xor(s0, off);
            s1 += __shfl_xor(s1, off);
            s2 += __shfl_xor(s2, off);
            s3 += __shfl_xor(s3, off);
        }
        int L = lane & 31;
        int h2i = L >> 3;
        float sh2 = (h2i == 0) ? s0 : (h2i == 1) ? s1 : (h2i == 2) ? s2 : s3;
        float ah2 = (h2i == 0) ? ald.x : (h2i == 1) ? ald.y : (h2i == 2) ? ald.z : ald.w;
        float rh2 = 1.f / (sh2 + 1e-16f);
        if (lane < 32) {
            float acc = 0.f;
            for (int e = 0; e < DCAP; ++e) {
                int s = cf[e];
                float av = als[4 * s + h2i];
                float ph = __expf(lrelu(av + ah2));
                acc = fmaf(ph, bf2f(h2b[(size_t)s * 32 + L]), acc);
            }
            for (int o = 0; o < oN; ++o) {
                int2 pr = ovf[o];
                if (pr.y == n) {
                    float av = als[4 * pr.x + h2i];
                    float ph = __expf(lrelu(av + ah2));
                    acc = fmaf(ph, bf2f(h2b[(size_t)pr.x * 32 + L]), acc);
                }
            }
            float row = acc * rh2 + b2[L];
            float mx = row;
            #pragma unroll
            for (int off = 16; off; off >>= 1) mx = fmaxf(mx, __shfl_xor(mx, off, 32));
            float pe = __expf(row - mx);
            float sm = pe;
            #pragma unroll
            for (int off = 16; off; off >>= 1) sm += __shfl_xor(sm, off, 32);
            out[(size_t)n * 32 + L] = row - mx - logf(sm);
        }
    }
}

extern "C" void kernel_launch(void* const* d_in, const int* in_sizes, int n_in,
                              void* d_out, int out_size, void* d_ws, size_t ws_size,
                              hipStream_t stream) {
    const void* x  = d_in[0];
    const void* ei = d_in[1];
    float* out = (float*)d_out;

    char* p = (char*)d_ws;
    auto take = [&](size_t b) -> char* {
        char* r = p; p += (b + 255) & ~(size_t)255; return r;
    };
    int*   degc  = (int*)take(sizeof(int) * (NN + 8));   // deg[NN] + ovfcnt
    int*   deg   = degc;
    int*   ovfcnt = degc + NN;
    unsigned short* csrF = (unsigned short*)take(sizeof(unsigned short) * (size_t)NN * DCAP);
    int2*  ovf   = (int2*)take(sizeof(int2) * MAXOVF);
    float* wsm   = (float*)take(sizeof(float) * 10528);
    unsigned short* h1b = (unsigned short*)take(sizeof(unsigned short) * (size_t)NN * 64);
    float* als1  = (float*)take(sizeof(float) * NN * 4);
    float* ald1  = (float*)take(sizeof(float) * NN * 4);
    float* out1  = (float*)take(sizeof(float) * (size_t)NN * 64);
    unsigned short* h2b = (unsigned short*)take(sizeof(unsigned short) * (size_t)NN * 32);
    float* als2  = (float*)take(sizeof(float) * NN * 4);
    float* ald2  = (float*)take(sizeof(float) * NN * 4);

    float* Wf2  = wsm + 8384;
    float* as2f = wsm + 10432;
    float* ad2f = wsm + 10464;
    float* b1f  = wsm + 8320;
    float* b2f  = wsm + 10496;

    hipMemsetAsync(degc, 0, sizeof(int) * (NN + 8), stream);
    k_gemm1cv<<<NG1R, 256, 0, stream>>>(x, ei, d_in[2], d_in[3], d_in[4], d_in[5],
                                        d_in[6], d_in[7], d_in[8], d_in[9],
                                        h1b, als1, ald1, csrF, deg, ovf, ovfcnt, wsm);
    k_agg1<<<(NN + 3) / 4, 256, 0, stream>>>(deg, csrF, ovf, ovfcnt, als1, ald1, h1b, b1f, out1);
    k_gemm2<<<(NN + 63) / 64, 256, 0, stream>>>(out1, Wf2, as2f, ad2f, h2b, als2, ald2);
    k_agg2<<<(NN + 3) / 4, 256, 0, stream>>>(deg, csrF, ovf, ovfcnt, als2, ald2, h2b, b2f, out);
}